// Round 12
// baseline (432.242 us; speedup 1.0000x reference)
//
#include <hip/hip_runtime.h>
#include <hip/hip_bf16.h>
#include <stdint.h>

// Problem constants
#define S_LEN 2048
#define BATCH 32
#define MROWS (S_LEN*BATCH)   // 65536 GEMM rows, K=N=1024

typedef __attribute__((ext_vector_type(8))) short bf16x8;
typedef __attribute__((ext_vector_type(4))) float f32x4;
typedef unsigned short ushort_t;

__device__ inline unsigned int pk2bf(float a, float b) {
  float2 t; t.x = a; t.y = b;
  __hip_bfloat162 h = __float22bfloat162_rn(t);
  union { __hip_bfloat162 h; unsigned int u; } c; c.h = h;
  return c.u;
}

__device__ inline void gload_lds16(const void* g, void* l) {
  __builtin_amdgcn_global_load_lds(
      (const __attribute__((address_space(1))) unsigned int*)g,
      (__attribute__((address_space(3))) unsigned int*)l, 16, 0, 0);
}

__device__ inline float fast_tanh(float x) {
  float e = __expf(2.0f * x);
  return 1.0f - 2.0f / (e + 1.0f);
}

// ---------------------------------------------------------------------------
// prep_small: blocks 0..63 convert Wc -> bf16;
//             blocks 64..95 compute wsum[b][n] = sum_d dec[b][d]*Wb[n][d]
// ---------------------------------------------------------------------------
__global__ __launch_bounds__(256) void prep_small_kernel(
    const float* __restrict__ dec, const float* __restrict__ Wb,
    const float* __restrict__ Wc, ushort_t* __restrict__ WcBf,
    float* __restrict__ wsum)
{
  const int t = threadIdx.x;
  const int bid = blockIdx.x;
  if (bid < 64) {
    const int base = bid * 16384;
    for (int i = 0; i < 16; ++i) {
      int idx = base + i * 1024 + t * 4;
      float4 v = *(const float4*)(Wc + idx);
      uint2 w; w.x = pk2bf(v.x, v.y); w.y = pk2bf(v.z, v.w);
      *(uint2*)(WcBf + idx) = w;
    }
  } else {
    const int j = bid - 64;                     // n-slice [j*32, j*32+32)
    __shared__ float sdec[32][65];
    __shared__ float swb[32][65];
    const int b = t & 31, nl = t >> 5;
    float acc0 = 0.f, acc1 = 0.f, acc2 = 0.f, acc3 = 0.f;
    for (int c = 0; c < 16; ++c) {
      __syncthreads();
      for (int idx = t; idx < 2048; idx += 256) {
        int rr = idx >> 6, dd = idx & 63;
        sdec[rr][dd] = dec[rr * 1024 + c * 64 + dd];
        swb[rr][dd]  = Wb[(size_t)(j * 32 + rr) * 1024 + c * 64 + dd];
      }
      __syncthreads();
      #pragma unroll 8
      for (int dd = 0; dd < 64; ++dd) {
        float dv = sdec[b][dd];
        acc0 += dv * swb[nl][dd];
        acc1 += dv * swb[nl + 8][dd];
        acc2 += dv * swb[nl + 16][dd];
        acc3 += dv * swb[nl + 24][dd];
      }
    }
    wsum[b * 1024 + j * 32 + nl]      = acc0;
    wsum[b * 1024 + j * 32 + nl + 8]  = acc1;
    wsum[b * 1024 + j * 32 + nl + 16] = acc2;
    wsum[b * 1024 + j * 32 + nl + 24] = acc3;
  }
}

// ---------------------------------------------------------------------------
// score (m97 structure, fp32-A direct): BM=128, BN=128, BK=64, 4 waves (2x2),
// wave 64x64. Single-buffered LDS (A fp32 32KB + B bf16 16KB), 2 barriers per
// K-step, 32 MFMA between barriers; latency hidden by 3 blocks/CU TLP.
// A: fp32 enc staged via async gload_lds with XOR-16 chunk pre-swizzle
//    (slot (r,c) holds global 16B chunk c^(r&15)); frag read = 2x float4 at
//    swizzled chunks, then v_cvt_pk to bf16 in regs. NO conversion pass.
// B: bf16 WcBf via gload_lds with XOR-8 pre-swizzle (proven 0-conflict).
// XCD-aware bid decode: the 8 blocks sharing an A-panel have identical bid%8
// -> same XCD -> fp32 A-panel fetched ~once per XCD into its private L2.
// Epilogue: scoreP8[row][n] = sum_col tanh(acc + wsum) * Wa (disjoint slices).
// ---------------------------------------------------------------------------
__global__ __launch_bounds__(256, 3) void score_kernel(
    const float* __restrict__ encF, const ushort_t* __restrict__ WcBf,
    const float* __restrict__ wsum, const float* __restrict__ Wa,
    float* __restrict__ scoreP8)
{
  __shared__ float   Af[128][64];    // 32 KB fp32 A tile
  __shared__ ushort_t Bb[128][64];   // 16 KB bf16 B tile
  __shared__ float scorep[128];

  const int tid = threadIdx.x;
  const int lane = tid & 63;
  const int l15 = lane & 15, q = lane >> 4;
  const int r7 = l15 & 7;
  const int wid = tid >> 6;
  const int wr = wid >> 1, wc = wid & 1;        // 2M x 2N waves
  const int bid = blockIdx.x;
  const int mi = bid & 15, nblk = (bid >> 4) & 7, mg = bid >> 7;
  const size_t rowBase = (size_t)(mg * 16 + mi) * 128;

  if (tid < 128) scorep[tid] = 0.f;

  // A staging: 2048 slots of 16B, 8/thread; slot s: r=s>>4, c=s&15;
  // source = global chunk (c ^ (r&15)) of row (rowBase+r)
  int aOff[8];                                   // float offsets
  #pragma unroll
  for (int k = 0; k < 8; ++k) {
    const int s = k * 256 + tid;
    const int r = s >> 4, c = s & 15;
    aOff[k] = r * 1024 + ((c ^ (r & 15)) * 4);
  }
  const float* aBase = encF + rowBase * 1024;

  // B staging: 1024 slots of 16B, 4/thread (XOR-8 over 8B bf16 chunks)
  int bOff[4], dOffB[4];
  #pragma unroll
  for (int k = 0; k < 4; ++k) {
    const int s = k * 256 + tid;
    const int r = s >> 3, c = s & 7;
    bOff[k] = (int)((nblk * 128 + r) * 1024 + ((c ^ (r & 7)) * 8));
    dOffB[k] = s * 8;
  }
  float* const aL = &Af[0][0];
  ushort_t* const bL = &Bb[0][0];

  int aRowOf[4], bRow[4];
  #pragma unroll
  for (int m = 0; m < 4; ++m) aRowOf[m] = (wr * 64 + m * 16 + l15) * 64;
  #pragma unroll
  for (int n = 0; n < 4; ++n) bRow[n] = (wc * 64 + n * 16 + l15) * 64;

  f32x4 acc[4][4];
  #pragma unroll
  for (int m = 0; m < 4; ++m)
    #pragma unroll
    for (int n = 0; n < 4; ++n) { f32x4 z = {0.f,0.f,0.f,0.f}; acc[m][n] = z; }

  for (int kt = 0; kt < 16; ++kt) {
    const int ko = kt * 64;
    #pragma unroll
    for (int k = 0; k < 8; ++k)
      gload_lds16(aBase + ko + aOff[k], (char*)aL + (k * 256 + tid) * 16);
    #pragma unroll
    for (int k = 0; k < 4; ++k)
      gload_lds16(WcBf + ko + bOff[k], bL + dOffB[k]);
    __syncthreads();   // full vmcnt drain: both tiles ready

    #pragma unroll
    for (int kk = 0; kk < 2; ++kk) {
      const int j = kk * 4 + q;                  // bf16-chunk-of-8 index
      bf16x8 af[4], bv[4];
      #pragma unroll
      for (int m = 0; m < 4; ++m) {
        const int cl = (2 * j) ^ l15;            // low 16B chunk (swizzled)
        const float4 lo = *(const float4*)(aL + aRowOf[m] + cl * 4);
        const float4 hi = *(const float4*)(aL + aRowOf[m] + (cl ^ 1) * 4);
        union { bf16x8 v; unsigned int u[4]; } cv;
        cv.u[0] = pk2bf(lo.x, lo.y); cv.u[1] = pk2bf(lo.z, lo.w);
        cv.u[2] = pk2bf(hi.x, hi.y); cv.u[3] = pk2bf(hi.z, hi.w);
        af[m] = cv.v;
      }
      const int cho = (j ^ r7) * 8;
      #pragma unroll
      for (int n = 0; n < 4; ++n) bv[n] = *(const bf16x8*)(bL + bRow[n] + cho);
      #pragma unroll
      for (int m = 0; m < 4; ++m)
        #pragma unroll
        for (int n = 0; n < 4; ++n)
          acc[m][n] = __builtin_amdgcn_mfma_f32_16x16x32_bf16(
              af[m], bv[n], acc[m][n], 0, 0, 0);
    }
    __syncthreads();   // compute done before next iter overwrites tiles
  }

  #pragma unroll
  for (int m = 0; m < 4; ++m) {
    #pragma unroll
    for (int i = 0; i < 4; ++i) {
      const int rowl = wr * 64 + m * 16 + q * 4 + i;
      const int bb2 = rowl & 31;                // global row %32 == rowl%32
      float v = 0.f;
      #pragma unroll
      for (int n = 0; n < 4; ++n) {
        const int col = nblk * 128 + wc * 64 + n * 16 + l15;
        float x = acc[m][n][i] + wsum[bb2 * 1024 + col];
        v += fast_tanh(x) * Wa[col];
      }
      v += __shfl_xor(v, 1); v += __shfl_xor(v, 2);
      v += __shfl_xor(v, 4); v += __shfl_xor(v, 8);
      if (l15 == 0) atomicAdd(&scorep[rowl], v);
    }
  }
  __syncthreads();
  if (tid < 128) scoreP8[(rowBase + tid) * 8 + nblk] = scorep[tid];
}

// ---------------------------------------------------------------------------
// ctx (softmax fused, fp32 enc): block (b, sc), 1024 blocks (64-s chunks).
// Phase 1: sweep all 2048 s, reduce 8 n-partials -> score -> exp; batch sum;
// stash own chunk's exp. Phase 2: out[b][:] += (exp/sum)*enc[s,b,:]
// (atomicAdd, out pre-zeroed by memset).
// ---------------------------------------------------------------------------
__global__ __launch_bounds__(256) void ctx_kernel(
    const float4* __restrict__ encF4, const float* __restrict__ scoreP8,
    float* __restrict__ out)
{
  const int b = blockIdx.x & 31, sc = blockIdx.x >> 5;
  const int t = threadIdx.x;
  __shared__ float eCh[64];
  __shared__ float red[256];

  const int chunk0 = sc * 64;
  float ssum = 0.f;
  for (int s = t; s < S_LEN; s += 256) {
    const float4* p = (const float4*)(scoreP8 + ((size_t)s * 32 + b) * 8);
    float4 u = p[0], v = p[1];
    float scv = ((u.x + u.y) + (u.z + u.w)) + ((v.x + v.y) + (v.z + v.w));
    float e = __expf(scv);                      // scores O(1): no max needed
    ssum += e;
    const int d = s - chunk0;
    if ((unsigned)d < 64u) eCh[d] = e;
  }
  red[t] = ssum;
  __syncthreads();
  #pragma unroll
  for (int o = 128; o > 0; o >>= 1) {
    if (t < o) red[t] += red[t + o];
    __syncthreads();
  }
  const float inv = 1.0f / red[0];

  float a0 = 0.f, a1 = 0.f, a2 = 0.f, a3 = 0.f;
  #pragma unroll 4
  for (int si = 0; si < 64; ++si) {
    const int s = chunk0 + si;
    const float a = eCh[si];
    const float4 v = encF4[((size_t)s * 32 + b) * 256 + t];
    a0 += a * v.x; a1 += a * v.y; a2 += a * v.z; a3 += a * v.w;
  }
  float* op = out + b * 1024 + t * 4;
  atomicAdd(op + 0, a0 * inv); atomicAdd(op + 1, a1 * inv);
  atomicAdd(op + 2, a2 * inv); atomicAdd(op + 3, a3 * inv);
}

// ---------------------------------------------------------------------------
extern "C" void kernel_launch(void* const* d_in, const int* in_sizes, int n_in,
                              void* d_out, int out_size, void* d_ws, size_t ws_size,
                              hipStream_t stream) {
  const float* dec = (const float*)d_in[0];
  const float* enc = (const float*)d_in[1];
  const float* Wb  = (const float*)d_in[2];
  const float* Wc  = (const float*)d_in[3];
  const float* Wa  = (const float*)d_in[4];
  float* out = (float*)d_out;
  (void)in_sizes; (void)n_in; (void)ws_size;

  char* ws = (char*)d_ws;
  ushort_t* WcBf    = (ushort_t*)ws;                    // 2 MB
  float*    wsum    = (float*)(ws + 2097152);           // 128 KB
  float*    scoreP8 = (float*)(ws + 2097152 + 131072);  // 2 MB

  hipMemsetAsync(out, 0, (size_t)out_size * sizeof(float), stream);
  prep_small_kernel<<<96, 256, 0, stream>>>(dec, Wb, Wc, WcBf, wsum);
  score_kernel<<<4096, 256, 0, stream>>>(enc, WcBf, wsum, Wa, scoreP8);
  ctx_kernel<<<1024, 256, 0, stream>>>((const float4*)enc, scoreP8, out);
}

// Round 13
// 387.111 us; speedup vs baseline: 1.1166x; 1.1166x over previous
//
#include <hip/hip_runtime.h>
#include <hip/hip_bf16.h>
#include <stdint.h>

// Problem constants
#define S_LEN 2048
#define BATCH 32
#define MROWS (S_LEN*BATCH)   // 65536 GEMM rows, K=N=1024

typedef __attribute__((ext_vector_type(8))) short bf16x8;
typedef __attribute__((ext_vector_type(4))) float f32x4;
typedef unsigned short ushort_t;

__device__ inline unsigned int pk2bf(float a, float b) {
  float2 t; t.x = a; t.y = b;
  __hip_bfloat162 h = __float22bfloat162_rn(t);
  union { __hip_bfloat162 h; unsigned int u; } c; c.h = h;
  return c.u;
}

__device__ inline float bflo(unsigned int u) { return __uint_as_float(u << 16); }
__device__ inline float bfhi(unsigned int u) { return __uint_as_float(u & 0xffff0000u); }

__device__ inline void gload_lds16(const void* g, void* l) {
  __builtin_amdgcn_global_load_lds(
      (const __attribute__((address_space(1))) unsigned int*)g,
      (__attribute__((address_space(3))) unsigned int*)l, 16, 0, 0);
}

__device__ inline float fast_tanh(float x) {
  float e = __expf(2.0f * x);
  return 1.0f - 2.0f / (e + 1.0f);
}

// ---------------------------------------------------------------------------
// prep_small: blocks 0..63 convert Wc -> bf16;
//             blocks 64..95 compute wsum[b][n] = sum_d dec[b][d]*Wb[n][d];
//             block  96     zeroes d_out (replaces the memset dispatch).
// ---------------------------------------------------------------------------
__global__ __launch_bounds__(256) void prep_small_kernel(
    const float* __restrict__ dec, const float* __restrict__ Wb,
    const float* __restrict__ Wc, ushort_t* __restrict__ WcBf,
    float* __restrict__ wsum, float* __restrict__ outZero, int outN)
{
  const int t = threadIdx.x;
  const int bid = blockIdx.x;
  if (bid < 64) {
    const int base = bid * 16384;
    for (int i = 0; i < 16; ++i) {
      int idx = base + i * 1024 + t * 4;
      float4 v = *(const float4*)(Wc + idx);
      uint2 w; w.x = pk2bf(v.x, v.y); w.y = pk2bf(v.z, v.w);
      *(uint2*)(WcBf + idx) = w;
    }
  } else if (bid < 96) {
    const int j = bid - 64;                     // n-slice [j*32, j*32+32)
    __shared__ float sdec[32][65];
    __shared__ float swb[32][65];
    const int b = t & 31, nl = t >> 5;
    float acc0 = 0.f, acc1 = 0.f, acc2 = 0.f, acc3 = 0.f;
    for (int c = 0; c < 16; ++c) {
      __syncthreads();
      for (int idx = t; idx < 2048; idx += 256) {
        int rr = idx >> 6, dd = idx & 63;
        sdec[rr][dd] = dec[rr * 1024 + c * 64 + dd];
        swb[rr][dd]  = Wb[(size_t)(j * 32 + rr) * 1024 + c * 64 + dd];
      }
      __syncthreads();
      #pragma unroll 8
      for (int dd = 0; dd < 64; ++dd) {
        float dv = sdec[b][dd];
        acc0 += dv * swb[nl][dd];
        acc1 += dv * swb[nl + 8][dd];
        acc2 += dv * swb[nl + 16][dd];
        acc3 += dv * swb[nl + 24][dd];
      }
    }
    wsum[b * 1024 + j * 32 + nl]      = acc0;
    wsum[b * 1024 + j * 32 + nl + 8]  = acc1;
    wsum[b * 1024 + j * 32 + nl + 16] = acc2;
    wsum[b * 1024 + j * 32 + nl + 24] = acc3;
  } else {
    // zero d_out (runs before ctx in stream order)
    float4 z = make_float4(0.f, 0.f, 0.f, 0.f);
    const int n4 = outN >> 2;
    for (int i = t; i < n4; i += 256)
      ((float4*)outZero)[i] = z;
  }
}

// ---------------------------------------------------------------------------
// score (R7-proven fused m97 structure): BM=128, BN=128, BK=64, 4 waves
// (2x2), wave 64x64. Single-buffered 32KB LDS, 2 barriers/K-step, 32 MFMA
// between barriers; latency hidden by 4 blocks/CU wave-level TLP (m114) —
// NOT source pipelining (R3/R4/R9 all regressed).
// A: fp32 enc -> regs -> bf16 -> swizzled ds_write (conversion fused; no
//    separate 384MB conv pass); nblk==0 blocks also persist the bf16 tile to
//    encBf for ctx. B: bf16 WcBf via async gload_lds w/ pre-swizzled source.
// XOR-8 chunk swizzle on both operands -> conflict-free frag reads.
// XCD-aware bid decode: the 8 blocks sharing an A-panel have identical bid%8
// -> same XCD -> fp32 A-panel fetched ~once per XCD into its private L2.
// Epilogue: scoreP8[row][n] = sum_col tanh(acc + wsum) * Wa (disjoint slices).
// ---------------------------------------------------------------------------
__global__ __launch_bounds__(256, 4) void score_kernel(
    const float4* __restrict__ encF4, ushort_t* __restrict__ encBf,
    const ushort_t* __restrict__ WcBf, const float* __restrict__ wsum,
    const float* __restrict__ Wa, float* __restrict__ scoreP8)
{
  __shared__ ushort_t Ab[128][64];   // 16 KB
  __shared__ ushort_t Bb[128][64];   // 16 KB
  __shared__ float scorep[128];

  const int tid = threadIdx.x;
  const int lane = tid & 63;
  const int l15 = lane & 15, q = lane >> 4;
  const int r7 = l15 & 7;
  const int wid = tid >> 6;
  const int wr = wid >> 1, wc = wid & 1;        // 2M x 2N waves
  const int bid = blockIdx.x;
  const int mi = bid & 15, nblk = (bid >> 4) & 7, mg = bid >> 7;
  const size_t rowBase = (size_t)(mg * 16 + mi) * 128;

  if (tid < 128) scorep[tid] = 0.f;

  // A staging (slot map, fully coalesced): row = k*16 + (tid>>4), f4 = tid&15
  const int tRow = tid >> 4;                    // 0..15
  const int f4 = tid & 15;
  const int swzT = (((f4 >> 1) ^ (tRow & 7)) * 8) + ((f4 & 1) * 4); // ushort units

  // B staging: 1024 slots of 16B, 4 per thread, gload_lds w/ pre-swz source
  int bOff[4], dOff[4];
  #pragma unroll
  for (int k = 0; k < 4; ++k) {
    const int s = k * 256 + tid;
    const int r = s >> 3, c = s & 7;
    bOff[k] = (int)((nblk * 128 + r) * 1024 + ((c ^ (r & 7)) * 8));
    dOff[k] = s * 8;
  }
  ushort_t* const aL = &Ab[0][0];
  ushort_t* const bL = &Bb[0][0];

  int aRow[4], bRow[4];
  #pragma unroll
  for (int m = 0; m < 4; ++m) aRow[m] = (wr * 64 + m * 16 + l15) * 64;
  #pragma unroll
  for (int n = 0; n < 4; ++n) bRow[n] = (wc * 64 + n * 16 + l15) * 64;
  const int ch0 = (q ^ r7) * 8;
  const int ch1 = ((4 + q) ^ r7) * 8;

  f32x4 acc[4][4];
  #pragma unroll
  for (int m = 0; m < 4; ++m)
    #pragma unroll
    for (int n = 0; n < 4; ++n) { f32x4 z = {0.f,0.f,0.f,0.f}; acc[m][n] = z; }

  for (int kt = 0; kt < 16; ++kt) {
    const int ko = kt * 64;
    // B: async LDS-DMA (safe: all waves passed the closing barrier)
    #pragma unroll
    for (int k = 0; k < 4; ++k)
      gload_lds16(WcBf + ko + bOff[k], bL + dOff[k]);

    // A: 8 coalesced float4 loads (16 lanes x 256B contiguous per row)
    float4 av[8];
    #pragma unroll
    for (int k = 0; k < 8; ++k)
      av[k] = encF4[(rowBase + k * 16 + tRow) * 256 + kt * 16 + f4];

    // convert -> swizzled LDS write; nblk==0 also persists bf16 to encBf
    #pragma unroll
    for (int k = 0; k < 8; ++k) {
      uint2 w;
      w.x = pk2bf(av[k].x, av[k].y);
      w.y = pk2bf(av[k].z, av[k].w);
      const int r = k * 16 + tRow;
      *(uint2*)(aL + r * 64 + swzT) = w;
      if (nblk == 0)
        *(uint2*)(encBf + (rowBase + r) * 1024 + ko + f4 * 4) = w;
    }
    __syncthreads();   // drains B vmcnt + A lgkm: both tiles ready

    #pragma unroll
    for (int kk = 0; kk < 2; ++kk) {
      const int cho = kk ? ch1 : ch0;
      bf16x8 af[4], bv[4];
      #pragma unroll
      for (int m = 0; m < 4; ++m) af[m] = *(const bf16x8*)(aL + aRow[m] + cho);
      #pragma unroll
      for (int n = 0; n < 4; ++n) bv[n] = *(const bf16x8*)(bL + bRow[n] + cho);
      #pragma unroll
      for (int m = 0; m < 4; ++m)
        #pragma unroll
        for (int n = 0; n < 4; ++n)
          acc[m][n] = __builtin_amdgcn_mfma_f32_16x16x32_bf16(
              af[m], bv[n], acc[m][n], 0, 0, 0);
    }
    __syncthreads();   // compute done before next iter overwrites tiles
  }

  #pragma unroll
  for (int m = 0; m < 4; ++m) {
    #pragma unroll
    for (int i = 0; i < 4; ++i) {
      const int rowl = wr * 64 + m * 16 + q * 4 + i;
      const int bb2 = rowl & 31;                // global row %32 == rowl%32
      float v = 0.f;
      #pragma unroll
      for (int n = 0; n < 4; ++n) {
        const int col = nblk * 128 + wc * 64 + n * 16 + l15;
        float x = acc[m][n][i] + wsum[bb2 * 1024 + col];
        v += fast_tanh(x) * Wa[col];
      }
      v += __shfl_xor(v, 1); v += __shfl_xor(v, 2);
      v += __shfl_xor(v, 4); v += __shfl_xor(v, 8);
      if (l15 == 0) atomicAdd(&scorep[rowl], v);
    }
  }
  __syncthreads();
  if (tid < 128) scoreP8[(rowBase + tid) * 8 + nblk] = scorep[tid];
}

// ---------------------------------------------------------------------------
// ctx (softmax fused, bf16 enc): block (b, sc), 1024 blocks (64-s chunks ->
// 4 blocks/CU for TLP). Phase 1: sweep all 2048 s, reduce 8 n-partials ->
// score -> exp; batch sum; stash own chunk's exp. Phase 2:
// out[b][:] += (exp/sum) * encBf[s,b,:] (atomicAdd; out zeroed by prep).
// ---------------------------------------------------------------------------
__global__ __launch_bounds__(256) void ctx_kernel(
    const ushort_t* __restrict__ encBf, const float* __restrict__ scoreP8,
    float* __restrict__ out)
{
  const int b = blockIdx.x & 31, sc = blockIdx.x >> 5;
  const int t = threadIdx.x;
  __shared__ float eCh[64];
  __shared__ float red[256];

  const int chunk0 = sc * 64;
  float ssum = 0.f;
  for (int s = t; s < S_LEN; s += 256) {
    const float4* p = (const float4*)(scoreP8 + ((size_t)s * 32 + b) * 8);
    float4 u = p[0], v = p[1];
    float scv = ((u.x + u.y) + (u.z + u.w)) + ((v.x + v.y) + (v.z + v.w));
    float e = __expf(scv);                      // scores O(1): no max needed
    ssum += e;
    const int d = s - chunk0;
    if ((unsigned)d < 64u) eCh[d] = e;
  }
  red[t] = ssum;
  __syncthreads();
  #pragma unroll
  for (int o = 128; o > 0; o >>= 1) {
    if (t < o) red[t] += red[t + o];
    __syncthreads();
  }
  const float inv = 1.0f / red[0];

  float a0 = 0.f, a1 = 0.f, a2 = 0.f, a3 = 0.f;
  const int e0 = t * 4;
  #pragma unroll 4
  for (int si = 0; si < 64; ++si) {
    const int s = chunk0 + si;
    const float a = eCh[si];
    uint2 w = *(const uint2*)(encBf + ((size_t)s * 32 + b) * 1024 + e0);
    a0 += a * bflo(w.x); a1 += a * bfhi(w.x);
    a2 += a * bflo(w.y); a3 += a * bfhi(w.y);
  }
  float* op = out + b * 1024 + e0;
  atomicAdd(op + 0, a0 * inv); atomicAdd(op + 1, a1 * inv);
  atomicAdd(op + 2, a2 * inv); atomicAdd(op + 3, a3 * inv);
}

// ---------------------------------------------------------------------------
extern "C" void kernel_launch(void* const* d_in, const int* in_sizes, int n_in,
                              void* d_out, int out_size, void* d_ws, size_t ws_size,
                              hipStream_t stream) {
  const float* dec = (const float*)d_in[0];
  const float* enc = (const float*)d_in[1];
  const float* Wb  = (const float*)d_in[2];
  const float* Wc  = (const float*)d_in[3];
  const float* Wa  = (const float*)d_in[4];
  float* out = (float*)d_out;
  (void)in_sizes; (void)n_in; (void)ws_size;

  char* ws = (char*)d_ws;
  ushort_t* encBf   = (ushort_t*)ws;                               // 128 MB
  ushort_t* WcBf    = (ushort_t*)(ws + 134217728);                 // 2 MB
  float*    wsum    = (float*)(ws + 134217728 + 2097152);          // 128 KB
  float*    scoreP8 = (float*)(ws + 134217728 + 2097152 + 131072); // 2 MB

  prep_small_kernel<<<97, 256, 0, stream>>>(dec, Wb, Wc, WcBf, wsum,
                                            out, out_size);
  score_kernel<<<4096, 256, 0, stream>>>((const float4*)enc, encBf, WcBf,
                                         wsum, Wa, scoreP8);
  ctx_kernel<<<1024, 256, 0, stream>>>(encBf, scoreP8, out);
}

// Round 14
// 383.202 us; speedup vs baseline: 1.1280x; 1.0102x over previous
//
#include <hip/hip_runtime.h>
#include <hip/hip_bf16.h>
#include <stdint.h>

// Problem constants
#define S_LEN 2048
#define BATCH 32
#define MROWS (S_LEN*BATCH)   // 65536 GEMM rows, K=N=1024

typedef __attribute__((ext_vector_type(8))) short bf16x8;
typedef __attribute__((ext_vector_type(4))) float f32x4;
typedef unsigned short ushort_t;

__device__ inline unsigned int pk2bf(float a, float b) {
  float2 t; t.x = a; t.y = b;
  __hip_bfloat162 h = __float22bfloat162_rn(t);
  union { __hip_bfloat162 h; unsigned int u; } c; c.h = h;
  return c.u;
}

__device__ inline float bflo(unsigned int u) { return __uint_as_float(u << 16); }
__device__ inline float bfhi(unsigned int u) { return __uint_as_float(u & 0xffff0000u); }

__device__ inline void gload_lds16(const void* g, void* l) {
  __builtin_amdgcn_global_load_lds(
      (const __attribute__((address_space(1))) unsigned int*)g,
      (__attribute__((address_space(3))) unsigned int*)l, 16, 0, 0);
}

__device__ inline float fast_tanh(float x) {
  float e = __expf(2.0f * x);
  return 1.0f - 2.0f / (e + 1.0f);
}

// ---------------------------------------------------------------------------
// prep_small: blocks 0..63 convert Wc -> bf16;
//             blocks 64..95 compute wsum[b][n] = sum_d dec[b][d]*Wb[n][d];
//             block  96     zeroes d_out (replaces the memset dispatch).
// ---------------------------------------------------------------------------
__global__ __launch_bounds__(256) void prep_small_kernel(
    const float* __restrict__ dec, const float* __restrict__ Wb,
    const float* __restrict__ Wc, ushort_t* __restrict__ WcBf,
    float* __restrict__ wsum, float* __restrict__ outZero, int outN)
{
  const int t = threadIdx.x;
  const int bid = blockIdx.x;
  if (bid < 64) {
    const int base = bid * 16384;
    for (int i = 0; i < 16; ++i) {
      int idx = base + i * 1024 + t * 4;
      float4 v = *(const float4*)(Wc + idx);
      uint2 w; w.x = pk2bf(v.x, v.y); w.y = pk2bf(v.z, v.w);
      *(uint2*)(WcBf + idx) = w;
    }
  } else if (bid < 96) {
    const int j = bid - 64;                     // n-slice [j*32, j*32+32)
    __shared__ float sdec[32][65];
    __shared__ float swb[32][65];
    const int b = t & 31, nl = t >> 5;
    float acc0 = 0.f, acc1 = 0.f, acc2 = 0.f, acc3 = 0.f;
    for (int c = 0; c < 16; ++c) {
      __syncthreads();
      for (int idx = t; idx < 2048; idx += 256) {
        int rr = idx >> 6, dd = idx & 63;
        sdec[rr][dd] = dec[rr * 1024 + c * 64 + dd];
        swb[rr][dd]  = Wb[(size_t)(j * 32 + rr) * 1024 + c * 64 + dd];
      }
      __syncthreads();
      #pragma unroll 8
      for (int dd = 0; dd < 64; ++dd) {
        float dv = sdec[b][dd];
        acc0 += dv * swb[nl][dd];
        acc1 += dv * swb[nl + 8][dd];
        acc2 += dv * swb[nl + 16][dd];
        acc3 += dv * swb[nl + 24][dd];
      }
    }
    wsum[b * 1024 + j * 32 + nl]      = acc0;
    wsum[b * 1024 + j * 32 + nl + 8]  = acc1;
    wsum[b * 1024 + j * 32 + nl + 16] = acc2;
    wsum[b * 1024 + j * 32 + nl + 24] = acc3;
  } else {
    float4 z = make_float4(0.f, 0.f, 0.f, 0.f);
    const int n4 = outN >> 2;
    for (int i = t; i < n4; i += 256)
      ((float4*)outZero)[i] = z;
  }
}

// ---------------------------------------------------------------------------
// score (R7/R13-proven fused m97 structure): BM=128, BN=128, BK=64, 4 waves
// (2x2), wave 64x64. Single-buffered 32KB LDS, 2 barriers/K-step, 32 MFMA
// between barriers; latency hidden by 4 blocks/CU wave-level TLP (m114).
// A: fp32 enc -> regs -> bf16 -> swizzled ds_write (conversion fused);
//    nblk==0 blocks also persist the bf16 tile to encBf for ctx.
// B: bf16 WcBf via async gload_lds w/ pre-swizzled source.
// XOR-8 chunk swizzle on both operands -> conflict-free frag reads.
// XCD-aware bid decode: the 8 blocks sharing an A-panel have identical bid%8
// -> same XCD -> fp32 A-panel fetched ~once per XCD into its private L2.
// Epilogue: scoreP8T[b][s][nblk] = sum_col tanh(acc + wsum) * Wa
// (TRANSPOSED [b][s][8] layout so ctx's sweep is coalesced).
// ---------------------------------------------------------------------------
__global__ __launch_bounds__(256, 4) void score_kernel(
    const float4* __restrict__ encF4, ushort_t* __restrict__ encBf,
    const ushort_t* __restrict__ WcBf, const float* __restrict__ wsum,
    const float* __restrict__ Wa, float* __restrict__ scoreP8T)
{
  __shared__ ushort_t Ab[128][64];   // 16 KB
  __shared__ ushort_t Bb[128][64];   // 16 KB
  __shared__ float scorep[128];

  const int tid = threadIdx.x;
  const int lane = tid & 63;
  const int l15 = lane & 15, q = lane >> 4;
  const int r7 = l15 & 7;
  const int wid = tid >> 6;
  const int wr = wid >> 1, wc = wid & 1;        // 2M x 2N waves
  const int bid = blockIdx.x;
  const int mi = bid & 15, nblk = (bid >> 4) & 7, mg = bid >> 7;
  const size_t rowBase = (size_t)(mg * 16 + mi) * 128;

  if (tid < 128) scorep[tid] = 0.f;

  // A staging (slot map, fully coalesced): row = k*16 + (tid>>4), f4 = tid&15
  const int tRow = tid >> 4;                    // 0..15
  const int f4 = tid & 15;
  const int swzT = (((f4 >> 1) ^ (tRow & 7)) * 8) + ((f4 & 1) * 4); // ushort units

  // B staging: 1024 slots of 16B, 4 per thread, gload_lds w/ pre-swz source
  int bOff[4], dOff[4];
  #pragma unroll
  for (int k = 0; k < 4; ++k) {
    const int s = k * 256 + tid;
    const int r = s >> 3, c = s & 7;
    bOff[k] = (int)((nblk * 128 + r) * 1024 + ((c ^ (r & 7)) * 8));
    dOff[k] = s * 8;
  }
  ushort_t* const aL = &Ab[0][0];
  ushort_t* const bL = &Bb[0][0];

  int aRow[4], bRow[4];
  #pragma unroll
  for (int m = 0; m < 4; ++m) aRow[m] = (wr * 64 + m * 16 + l15) * 64;
  #pragma unroll
  for (int n = 0; n < 4; ++n) bRow[n] = (wc * 64 + n * 16 + l15) * 64;
  const int ch0 = (q ^ r7) * 8;
  const int ch1 = ((4 + q) ^ r7) * 8;

  f32x4 acc[4][4];
  #pragma unroll
  for (int m = 0; m < 4; ++m)
    #pragma unroll
    for (int n = 0; n < 4; ++n) { f32x4 z = {0.f,0.f,0.f,0.f}; acc[m][n] = z; }

  for (int kt = 0; kt < 16; ++kt) {
    const int ko = kt * 64;
    // B: async LDS-DMA (safe: all waves passed the closing barrier)
    #pragma unroll
    for (int k = 0; k < 4; ++k)
      gload_lds16(WcBf + ko + bOff[k], bL + dOff[k]);

    // A: 8 coalesced float4 loads (16 lanes x 256B contiguous per row)
    float4 av[8];
    #pragma unroll
    for (int k = 0; k < 8; ++k)
      av[k] = encF4[(rowBase + k * 16 + tRow) * 256 + kt * 16 + f4];

    // convert -> swizzled LDS write; nblk==0 also persists bf16 to encBf
    #pragma unroll
    for (int k = 0; k < 8; ++k) {
      uint2 w;
      w.x = pk2bf(av[k].x, av[k].y);
      w.y = pk2bf(av[k].z, av[k].w);
      const int r = k * 16 + tRow;
      *(uint2*)(aL + r * 64 + swzT) = w;
      if (nblk == 0)
        *(uint2*)(encBf + (rowBase + r) * 1024 + ko + f4 * 4) = w;
    }
    __syncthreads();   // drains B vmcnt + A lgkm: both tiles ready

    #pragma unroll
    for (int kk = 0; kk < 2; ++kk) {
      const int cho = kk ? ch1 : ch0;
      bf16x8 af[4], bv[4];
      #pragma unroll
      for (int m = 0; m < 4; ++m) af[m] = *(const bf16x8*)(aL + aRow[m] + cho);
      #pragma unroll
      for (int n = 0; n < 4; ++n) bv[n] = *(const bf16x8*)(bL + bRow[n] + cho);
      #pragma unroll
      for (int m = 0; m < 4; ++m)
        #pragma unroll
        for (int n = 0; n < 4; ++n)
          acc[m][n] = __builtin_amdgcn_mfma_f32_16x16x32_bf16(
              af[m], bv[n], acc[m][n], 0, 0, 0);
    }
    __syncthreads();   // compute done before next iter overwrites tiles
  }

  #pragma unroll
  for (int m = 0; m < 4; ++m) {
    #pragma unroll
    for (int i = 0; i < 4; ++i) {
      const int rowl = wr * 64 + m * 16 + q * 4 + i;
      const int bb2 = rowl & 31;                // global row %32 == rowl%32
      float v = 0.f;
      #pragma unroll
      for (int n = 0; n < 4; ++n) {
        const int col = nblk * 128 + wc * 64 + n * 16 + l15;
        float x = acc[m][n][i] + wsum[bb2 * 1024 + col];
        v += fast_tanh(x) * Wa[col];
      }
      v += __shfl_xor(v, 1); v += __shfl_xor(v, 2);
      v += __shfl_xor(v, 4); v += __shfl_xor(v, 8);
      if (l15 == 0) atomicAdd(&scorep[rowl], v);
    }
  }
  __syncthreads();
  if (tid < 128) {
    // transposed partial layout: [b][s][8] so ctx reads are coalesced
    const int grow = (int)rowBase + tid;
    const int b = grow & 31, s = grow >> 5;
    scoreP8T[((b * 2048 + s) << 3) + nblk] = scorep[tid];
  }
}

// ---------------------------------------------------------------------------
// ctx (softmax fused, bf16 enc): block (b, sc), 1024 blocks (64-s chunks ->
// 4 blocks/CU). Phase 1 (COALESCED over [b][s][8]): sweep all 2048 s, reduce
// 8 n-partials -> score -> exp; batch sum; stash own chunk's exp. Phase 2:
// out[b][:] += (exp/sum) * encBf[s,b,:] (atomicAdd; out zeroed by prep).
// ---------------------------------------------------------------------------
__global__ __launch_bounds__(256) void ctx_kernel(
    const ushort_t* __restrict__ encBf, const float* __restrict__ scoreP8T,
    float* __restrict__ out)
{
  const int b = blockIdx.x & 31, sc = blockIdx.x >> 5;
  const int t = threadIdx.x;
  __shared__ float eCh[64];
  __shared__ float red[256];

  const int chunk0 = sc * 64;
  const float* colBase = scoreP8T + ((size_t)b * 2048 << 3);
  float ssum = 0.f;
  for (int s = t; s < S_LEN; s += 256) {
    const float4* p = (const float4*)(colBase + ((size_t)s << 3));
    float4 u = p[0], v = p[1];
    float scv = ((u.x + u.y) + (u.z + u.w)) + ((v.x + v.y) + (v.z + v.w));
    float e = __expf(scv);                      // scores O(1): no max needed
    ssum += e;
    const int d = s - chunk0;
    if ((unsigned)d < 64u) eCh[d] = e;
  }
  red[t] = ssum;
  __syncthreads();
  #pragma unroll
  for (int o = 128; o > 0; o >>= 1) {
    if (t < o) red[t] += red[t + o];
    __syncthreads();
  }
  const float inv = 1.0f / red[0];

  float a0 = 0.f, a1 = 0.f, a2 = 0.f, a3 = 0.f;
  const int e0 = t * 4;
  #pragma unroll 4
  for (int si = 0; si < 64; ++si) {
    const int s = chunk0 + si;
    const float a = eCh[si];
    uint2 w = *(const uint2*)(encBf + ((size_t)s * 32 + b) * 1024 + e0);
    a0 += a * bflo(w.x); a1 += a * bfhi(w.x);
    a2 += a * bflo(w.y); a3 += a * bfhi(w.y);
  }
  float* op = out + b * 1024 + e0;
  atomicAdd(op + 0, a0 * inv); atomicAdd(op + 1, a1 * inv);
  atomicAdd(op + 2, a2 * inv); atomicAdd(op + 3, a3 * inv);
}

// ---------------------------------------------------------------------------
extern "C" void kernel_launch(void* const* d_in, const int* in_sizes, int n_in,
                              void* d_out, int out_size, void* d_ws, size_t ws_size,
                              hipStream_t stream) {
  const float* dec = (const float*)d_in[0];
  const float* enc = (const float*)d_in[1];
  const float* Wb  = (const float*)d_in[2];
  const float* Wc  = (const float*)d_in[3];
  const float* Wa  = (const float*)d_in[4];
  float* out = (float*)d_out;
  (void)in_sizes; (void)n_in; (void)ws_size;

  char* ws = (char*)d_ws;
  ushort_t* encBf    = (ushort_t*)ws;                               // 128 MB
  ushort_t* WcBf     = (ushort_t*)(ws + 134217728);                 // 2 MB
  float*    wsum     = (float*)(ws + 134217728 + 2097152);          // 128 KB
  float*    scoreP8T = (float*)(ws + 134217728 + 2097152 + 131072); // 2 MB

  prep_small_kernel<<<97, 256, 0, stream>>>(dec, Wb, Wc, WcBf, wsum,
                                            out, out_size);
  score_kernel<<<4096, 256, 0, stream>>>((const float4*)enc, encBf, WcBf,
                                         wsum, Wa, scoreP8T);
  ctx_kernel<<<1024, 256, 0, stream>>>(encBf, scoreP8T, out);
}

// Round 15
// 367.899 us; speedup vs baseline: 1.1749x; 1.0416x over previous
//
#include <hip/hip_runtime.h>
#include <hip/hip_bf16.h>
#include <stdint.h>

// Problem constants
#define S_LEN 2048
#define BATCH 32
#define MROWS (S_LEN*BATCH)   // 65536 GEMM rows, K=N=1024

typedef __attribute__((ext_vector_type(8))) short bf16x8;
typedef __attribute__((ext_vector_type(4))) float f32x4;
typedef unsigned short ushort_t;

__device__ inline unsigned int pk2bf(float a, float b) {
  float2 t; t.x = a; t.y = b;
  __hip_bfloat162 h = __float22bfloat162_rn(t);
  union { __hip_bfloat162 h; unsigned int u; } c; c.h = h;
  return c.u;
}

__device__ inline float bflo(unsigned int u) { return __uint_as_float(u << 16); }
__device__ inline float bfhi(unsigned int u) { return __uint_as_float(u & 0xffff0000u); }

__device__ inline void gload_lds16(const void* g, void* l) {
  __builtin_amdgcn_global_load_lds(
      (const __attribute__((address_space(1))) unsigned int*)g,
      (__attribute__((address_space(3))) unsigned int*)l, 16, 0, 0);
}

__device__ inline float fast_tanh(float x) {
  float e = __expf(2.0f * x);
  return 1.0f - 2.0f / (e + 1.0f);
}

// ---------------------------------------------------------------------------
// prep_small: blocks 0..63 convert Wc -> bf16;
//             blocks 64..95 compute wsum[b][n] = sum_d dec[b][d]*Wb[n][d]
// ---------------------------------------------------------------------------
__global__ __launch_bounds__(256) void prep_small_kernel(
    const float* __restrict__ dec, const float* __restrict__ Wb,
    const float* __restrict__ Wc, ushort_t* __restrict__ WcBf,
    float* __restrict__ wsum)
{
  const int t = threadIdx.x;
  const int bid = blockIdx.x;
  if (bid < 64) {
    const int base = bid * 16384;
    for (int i = 0; i < 16; ++i) {
      int idx = base + i * 1024 + t * 4;
      float4 v = *(const float4*)(Wc + idx);
      uint2 w; w.x = pk2bf(v.x, v.y); w.y = pk2bf(v.z, v.w);
      *(uint2*)(WcBf + idx) = w;
    }
  } else {
    const int j = bid - 64;                     // n-slice [j*32, j*32+32)
    __shared__ float sdec[32][65];
    __shared__ float swb[32][65];
    const int b = t & 31, nl = t >> 5;
    float acc0 = 0.f, acc1 = 0.f, acc2 = 0.f, acc3 = 0.f;
    for (int c = 0; c < 16; ++c) {
      __syncthreads();
      for (int idx = t; idx < 2048; idx += 256) {
        int rr = idx >> 6, dd = idx & 63;
        sdec[rr][dd] = dec[rr * 1024 + c * 64 + dd];
        swb[rr][dd]  = Wb[(size_t)(j * 32 + rr) * 1024 + c * 64 + dd];
      }
      __syncthreads();
      #pragma unroll 8
      for (int dd = 0; dd < 64; ++dd) {
        float dv = sdec[b][dd];
        acc0 += dv * swb[nl][dd];
        acc1 += dv * swb[nl + 8][dd];
        acc2 += dv * swb[nl + 16][dd];
        acc3 += dv * swb[nl + 24][dd];
      }
    }
    wsum[b * 1024 + j * 32 + nl]      = acc0;
    wsum[b * 1024 + j * 32 + nl + 8]  = acc1;
    wsum[b * 1024 + j * 32 + nl + 16] = acc2;
    wsum[b * 1024 + j * 32 + nl + 24] = acc3;
  }
}

// ---------------------------------------------------------------------------
// score (R7/R14-proven fused m97 structure, byte-identical): BM=128, BN=128,
// BK=64, 4 waves (2x2), wave 64x64. Single-buffered 32KB LDS, 2 barriers per
// K-step, 32 MFMA between barriers; latency hidden by 4 blocks/CU TLP (m114).
// A: fp32 enc -> regs -> bf16 -> swizzled ds_write (conversion fused);
//    nblk==0 blocks also persist the bf16 tile to encBf for ctx.
// B: bf16 WcBf via async gload_lds w/ pre-swizzled source.
// XOR-8 chunk swizzle on both operands -> conflict-free frag reads.
// XCD-aware bid decode: 8 blocks sharing an A-panel -> same XCD L2.
// Epilogue: scoreP8T[b][s][nblk] = sum_col tanh(acc + wsum) * Wa.
// ---------------------------------------------------------------------------
__global__ __launch_bounds__(256, 4) void score_kernel(
    const float4* __restrict__ encF4, ushort_t* __restrict__ encBf,
    const ushort_t* __restrict__ WcBf, const float* __restrict__ wsum,
    const float* __restrict__ Wa, float* __restrict__ scoreP8T)
{
  __shared__ ushort_t Ab[128][64];   // 16 KB
  __shared__ ushort_t Bb[128][64];   // 16 KB
  __shared__ float scorep[128];

  const int tid = threadIdx.x;
  const int lane = tid & 63;
  const int l15 = lane & 15, q = lane >> 4;
  const int r7 = l15 & 7;
  const int wid = tid >> 6;
  const int wr = wid >> 1, wc = wid & 1;        // 2M x 2N waves
  const int bid = blockIdx.x;
  const int mi = bid & 15, nblk = (bid >> 4) & 7, mg = bid >> 7;
  const size_t rowBase = (size_t)(mg * 16 + mi) * 128;

  if (tid < 128) scorep[tid] = 0.f;

  const int tRow = tid >> 4;                    // 0..15
  const int f4 = tid & 15;
  const int swzT = (((f4 >> 1) ^ (tRow & 7)) * 8) + ((f4 & 1) * 4); // ushort units

  int bOff[4], dOff[4];
  #pragma unroll
  for (int k = 0; k < 4; ++k) {
    const int s = k * 256 + tid;
    const int r = s >> 3, c = s & 7;
    bOff[k] = (int)((nblk * 128 + r) * 1024 + ((c ^ (r & 7)) * 8));
    dOff[k] = s * 8;
  }
  ushort_t* const aL = &Ab[0][0];
  ushort_t* const bL = &Bb[0][0];

  int aRow[4], bRow[4];
  #pragma unroll
  for (int m = 0; m < 4; ++m) aRow[m] = (wr * 64 + m * 16 + l15) * 64;
  #pragma unroll
  for (int n = 0; n < 4; ++n) bRow[n] = (wc * 64 + n * 16 + l15) * 64;
  const int ch0 = (q ^ r7) * 8;
  const int ch1 = ((4 + q) ^ r7) * 8;

  f32x4 acc[4][4];
  #pragma unroll
  for (int m = 0; m < 4; ++m)
    #pragma unroll
    for (int n = 0; n < 4; ++n) { f32x4 z = {0.f,0.f,0.f,0.f}; acc[m][n] = z; }

  for (int kt = 0; kt < 16; ++kt) {
    const int ko = kt * 64;
    #pragma unroll
    for (int k = 0; k < 4; ++k)
      gload_lds16(WcBf + ko + bOff[k], bL + dOff[k]);

    float4 av[8];
    #pragma unroll
    for (int k = 0; k < 8; ++k)
      av[k] = encF4[(rowBase + k * 16 + tRow) * 256 + kt * 16 + f4];

    #pragma unroll
    for (int k = 0; k < 8; ++k) {
      uint2 w;
      w.x = pk2bf(av[k].x, av[k].y);
      w.y = pk2bf(av[k].z, av[k].w);
      const int r = k * 16 + tRow;
      *(uint2*)(aL + r * 64 + swzT) = w;
      if (nblk == 0)
        *(uint2*)(encBf + (rowBase + r) * 1024 + ko + f4 * 4) = w;
    }
    __syncthreads();   // drains B vmcnt + A lgkm: both tiles ready

    #pragma unroll
    for (int kk = 0; kk < 2; ++kk) {
      const int cho = kk ? ch1 : ch0;
      bf16x8 af[4], bv[4];
      #pragma unroll
      for (int m = 0; m < 4; ++m) af[m] = *(const bf16x8*)(aL + aRow[m] + cho);
      #pragma unroll
      for (int n = 0; n < 4; ++n) bv[n] = *(const bf16x8*)(bL + bRow[n] + cho);
      #pragma unroll
      for (int m = 0; m < 4; ++m)
        #pragma unroll
        for (int n = 0; n < 4; ++n)
          acc[m][n] = __builtin_amdgcn_mfma_f32_16x16x32_bf16(
              af[m], bv[n], acc[m][n], 0, 0, 0);
    }
    __syncthreads();   // compute done before next iter overwrites tiles
  }

  #pragma unroll
  for (int m = 0; m < 4; ++m) {
    #pragma unroll
    for (int i = 0; i < 4; ++i) {
      const int rowl = wr * 64 + m * 16 + q * 4 + i;
      const int bb2 = rowl & 31;                // global row %32 == rowl%32
      float v = 0.f;
      #pragma unroll
      for (int n = 0; n < 4; ++n) {
        const int col = nblk * 128 + wc * 64 + n * 16 + l15;
        float x = acc[m][n][i] + wsum[bb2 * 1024 + col];
        v += fast_tanh(x) * Wa[col];
      }
      v += __shfl_xor(v, 1); v += __shfl_xor(v, 2);
      v += __shfl_xor(v, 4); v += __shfl_xor(v, 8);
      if (l15 == 0) atomicAdd(&scorep[rowl], v);
    }
  }
  __syncthreads();
  if (tid < 128) {
    const int grow = (int)rowBase + tid;
    const int b = grow & 31, s = grow >> 5;
    scoreP8T[((b * 2048 + s) << 3) + nblk] = scorep[tid];
  }
}

// ---------------------------------------------------------------------------
// ctx_partial (deterministic, NO global atomics): block (b, sc).
// Exp only for own 64 s (normalization deferred); wave-reduce chunk exp-sum
// -> gSum[sc*32+b]; accumulate partial[sc][b][e] with plain float4 stores.
// ---------------------------------------------------------------------------
__global__ __launch_bounds__(256) void ctx_partial_kernel(
    const ushort_t* __restrict__ encBf, const float* __restrict__ scoreP8T,
    float* __restrict__ partial, float* __restrict__ gSum)
{
  const int b = blockIdx.x & 31, sc = blockIdx.x >> 5;
  const int t = threadIdx.x;
  __shared__ float eCh[64];

  const int chunk0 = sc * 64;
  if (t < 64) {
    const float4* p = (const float4*)(scoreP8T +
                        (((size_t)b * 2048 + chunk0 + t) << 3));
    float4 u = p[0], v = p[1];
    float scv = ((u.x + u.y) + (u.z + u.w)) + ((v.x + v.y) + (v.z + v.w));
    float e = __expf(scv);                      // scores O(1): no max needed
    eCh[t] = e;
    // wave-0 reduction over 64 lanes
    float sum = e;
    sum += __shfl_xor(sum, 1);  sum += __shfl_xor(sum, 2);
    sum += __shfl_xor(sum, 4);  sum += __shfl_xor(sum, 8);
    sum += __shfl_xor(sum, 16); sum += __shfl_xor(sum, 32);
    if (t == 0) gSum[sc * 32 + b] = sum;
  }
  __syncthreads();

  float a0 = 0.f, a1 = 0.f, a2 = 0.f, a3 = 0.f;
  const int e0 = t * 4;
  #pragma unroll 4
  for (int si = 0; si < 64; ++si) {
    const int s = chunk0 + si;
    const float a = eCh[si];
    uint2 w = *(const uint2*)(encBf + ((size_t)s * 32 + b) * 1024 + e0);
    a0 += a * bflo(w.x); a1 += a * bfhi(w.x);
    a2 += a * bflo(w.y); a3 += a * bfhi(w.y);
  }
  *(float4*)(partial + ((size_t)(sc * 32 + b)) * 1024 + e0) =
      make_float4(a0, a1, a2, a3);
}

// ---------------------------------------------------------------------------
// ctx_reduce: block b. Sum 32 chunk partials + 32 chunk exp-sums, scale by
// 1/total, write out directly (no pre-zeroing needed anywhere).
// ---------------------------------------------------------------------------
__global__ __launch_bounds__(256) void ctx_reduce_kernel(
    const float* __restrict__ partial, const float* __restrict__ gSum,
    float* __restrict__ out)
{
  const int b = blockIdx.x, t = threadIdx.x;
  float tot = 0.f;
  #pragma unroll
  for (int sc = 0; sc < 32; ++sc) tot += gSum[sc * 32 + b];
  const float inv = 1.0f / tot;

  float4 acc = make_float4(0.f, 0.f, 0.f, 0.f);
  #pragma unroll
  for (int sc = 0; sc < 32; ++sc) {
    float4 v = *(const float4*)(partial + ((size_t)(sc * 32 + b)) * 1024 + t * 4);
    acc.x += v.x; acc.y += v.y; acc.z += v.z; acc.w += v.w;
  }
  acc.x *= inv; acc.y *= inv; acc.z *= inv; acc.w *= inv;
  *(float4*)(out + (size_t)b * 1024 + t * 4) = acc;
}

// ---------------------------------------------------------------------------
extern "C" void kernel_launch(void* const* d_in, const int* in_sizes, int n_in,
                              void* d_out, int out_size, void* d_ws, size_t ws_size,
                              hipStream_t stream) {
  const float* dec = (const float*)d_in[0];
  const float* enc = (const float*)d_in[1];
  const float* Wb  = (const float*)d_in[2];
  const float* Wc  = (const float*)d_in[3];
  const float* Wa  = (const float*)d_in[4];
  float* out = (float*)d_out;
  (void)in_sizes; (void)n_in; (void)ws_size; (void)out_size;

  char* ws = (char*)d_ws;
  ushort_t* encBf    = (ushort_t*)ws;                                    // 128 MB
  ushort_t* WcBf     = (ushort_t*)(ws + 134217728);                      // 2 MB
  float*    wsum     = (float*)(ws + 134217728 + 2097152);               // 128 KB
  float*    scoreP8T = (float*)(ws + 134217728 + 2097152 + 131072);      // 2 MB
  float*    partial  = (float*)(ws + 134217728 + 2097152 + 131072 + 2097152);        // 4 MB
  float*    gSum     = (float*)(ws + 134217728 + 2097152 + 131072 + 2097152 + 4194304); // 4 KB

  prep_small_kernel<<<96, 256, 0, stream>>>(dec, Wb, Wc, WcBf, wsum);
  score_kernel<<<4096, 256, 0, stream>>>((const float4*)enc, encBf, WcBf,
                                         wsum, Wa, scoreP8T);
  ctx_partial_kernel<<<1024, 256, 0, stream>>>(encBf, scoreP8T, partial, gSum);
  ctx_reduce_kernel<<<32, 256, 0, stream>>>(partial, gSum, out);
}